// Round 1
// baseline (4121.638 us; speedup 1.0000x reference)
//
#include <hip/hip_runtime.h>
#include <math.h>

namespace {

constexpr int B = 16, H = 512, W = 512;
constexpr int HWc = H * W;                 // 262144
constexpr size_t Nc = (size_t)B * HWc;     // 4194304

// --- block-wide sum over 256 threads (4 waves of 64). Valid on tid==0 only.
__device__ __forceinline__ float block_reduce_256(float v, float* sm, int tid) {
#pragma unroll
  for (int off = 32; off > 0; off >>= 1) v += __shfl_down(v, off);
  int lane = tid & 63, wid = tid >> 6;
  if (lane == 0) sm[wid] = v;
  __syncthreads();
  float r = 0.f;
  if (tid == 0) r = sm[0] + sm[1] + sm[2] + sm[3];
  __syncthreads();  // allow sm reuse
  return r;
}

// acc layout (doubles): [0]=bce, [1..16]=sum_p, [17..32]=sum_t, [33..48]=sum_pt,
// [49..58]=sum|pred_d - gt_b| (d=1..10), [59..68]=sum|gt_d - pred_b|
__global__ void elem_reduce_kernel(const float* __restrict__ logits,
                                   const int* __restrict__ target,
                                   float* __restrict__ probs,
                                   double* __restrict__ acc) {
  __shared__ float sm[4];
  int tid = threadIdx.x;
  int blk = blockIdx.x;
  int b = blk >> 6;       // 64 blocks per image
  int chunk = blk & 63;   // each block: 4096 contiguous elems
  int base = b * HWc + chunk * 4096;
  float s_bce = 0.f, s_p = 0.f, s_t = 0.f, s_pt = 0.f;
#pragma unroll
  for (int k = 0; k < 4; ++k) {
    int idx = base + k * 1024 + tid * 4;
    float4 x4 = *reinterpret_cast<const float4*>(logits + idx);
    int4 t4 = *reinterpret_cast<const int4*>(target + idx);
    float xs[4] = {x4.x, x4.y, x4.z, x4.w};
    int ts[4] = {t4.x, t4.y, t4.z, t4.w};
    float ps[4];
#pragma unroll
    for (int j = 0; j < 4; ++j) {
      float x = xs[j];
      float t = (float)ts[j];
      s_bce += fmaxf(x, 0.f) - x * t + log1pf(expf(-fabsf(x)));
      float p = 1.f / (1.f + expf(-x));
      ps[j] = p;
      s_p += p;
      s_t += t;
      s_pt += p * t;
    }
    *reinterpret_cast<float4*>(probs + idx) =
        make_float4(ps[0], ps[1], ps[2], ps[3]);
  }
  float r;
  r = block_reduce_256(s_bce, sm, tid);
  if (tid == 0) atomicAdd(&acc[0], (double)r);
  r = block_reduce_256(s_p, sm, tid);
  if (tid == 0) atomicAdd(&acc[1 + b], (double)r);
  r = block_reduce_256(s_t, sm, tid);
  if (tid == 0) atomicAdd(&acc[17 + b], (double)r);
  r = block_reduce_256(s_pt, sm, tid);
  if (tid == 0) atomicAdd(&acc[33 + b], (double)r);
}

// soft boundary of probs: max3x3 - min3x3 (clamped indices == truncated window)
__global__ void boundary_probs_kernel(const float* __restrict__ probs,
                                      float* __restrict__ outb) {
  int tid = threadIdx.x;
  int tx = tid & 63, ty = tid >> 6;
  int x = blockIdx.x * 64 + tx;
  int y = blockIdx.y * 4 + ty;
  int b = blockIdx.z;
  const float* img = probs + (size_t)b * HWc;
  float mx = -1e30f, mn = 1e30f;
#pragma unroll
  for (int dy = -1; dy <= 1; ++dy) {
    int yy = min(max(y + dy, 0), H - 1);
#pragma unroll
    for (int dx = -1; dx <= 1; ++dx) {
      int xx = min(max(x + dx, 0), W - 1);
      float v = img[yy * W + xx];
      mx = fmaxf(mx, v);
      mn = fminf(mn, v);
    }
  }
  outb[(size_t)b * HWc + y * W + x] = mx - mn;
}

__global__ void boundary_gt_kernel(const int* __restrict__ target,
                                   float* __restrict__ outb) {
  int tid = threadIdx.x;
  int tx = tid & 63, ty = tid >> 6;
  int x = blockIdx.x * 64 + tx;
  int y = blockIdx.y * 4 + ty;
  int b = blockIdx.z;
  const int* img = target + (size_t)b * HWc;
  int mx = -2147483647, mn = 2147483647;
#pragma unroll
  for (int dy = -1; dy <= 1; ++dy) {
    int yy = min(max(y + dy, 0), H - 1);
#pragma unroll
    for (int dx = -1; dx <= 1; ++dx) {
      int xx = min(max(x + dx, 0), W - 1);
      int v = img[yy * W + xx];
      mx = max(mx, v);
      mn = min(mn, v);
    }
  }
  outb[(size_t)b * HWc + y * W + x] = (float)(mx - mn);
}

// nxt = dilate1(cur); accumulate sum |nxt - other| into acc_slot
__global__ void dilate_diff_kernel(const float* __restrict__ cur,
                                   const float* __restrict__ other,
                                   float* __restrict__ nxt,
                                   double* __restrict__ acc_slot) {
  __shared__ float sm[4];
  int tid = threadIdx.x;
  int tx = tid & 63, ty = tid >> 6;
  int x = blockIdx.x * 64 + tx;
  int y = blockIdx.y * 4 + ty;
  int b = blockIdx.z;
  const float* img = cur + (size_t)b * HWc;
  float mx = -1e30f;
#pragma unroll
  for (int dy = -1; dy <= 1; ++dy) {
    int yy = min(max(y + dy, 0), H - 1);
#pragma unroll
    for (int dx = -1; dx <= 1; ++dx) {
      int xx = min(max(x + dx, 0), W - 1);
      mx = fmaxf(mx, img[yy * W + xx]);
    }
  }
  size_t idx = (size_t)b * HWc + y * W + x;
  nxt[idx] = mx;
  float diff = fabsf(mx - other[idx]);
  float r = block_reduce_256(diff, sm, tid);
  if (tid == 0) atomicAdd(acc_slot, (double)r);
}

__global__ void finalize_kernel(const double* __restrict__ acc,
                                float* __restrict__ out) {
  if (threadIdx.x == 0 && blockIdx.x == 0) {
    const double Nd = (double)Nc;
    double bce = acc[0] / Nd;
    double dice_l = 0.0, ft_l = 0.0;
    for (int b = 0; b < B; ++b) {
      double sp = acc[1 + b], st = acc[17 + b], spt = acc[33 + b];
      double dice = (2.0 * spt + 1e-6) / (sp + st + 1e-6 + 1e-7);
      dice_l += 1.0 - dice;
      double TP = spt, FP = sp - spt, FN = st - spt;
      double tv = (TP + 1e-6) / (TP + 0.7 * FP + 0.3 * FN + 1e-6 + 1e-7);
      ft_l += pow(1.0 - tv, 0.75);
    }
    dice_l /= (double)B;
    ft_l /= (double)B;
    double hd = 0.0;
    for (int d = 1; d <= 10; ++d) {
      double w = (double)d / 10.0;
      hd += w * ((acc[48 + d] + acc[58 + d]) / Nd);
    }
    hd /= (5.5 + 1e-8);
    out[0] = (float)(bce + dice_l + ft_l + 0.1 * hd);
  }
}

}  // namespace

extern "C" void kernel_launch(void* const* d_in, const int* in_sizes, int n_in,
                              void* d_out, int out_size, void* d_ws,
                              size_t ws_size, hipStream_t stream) {
  const float* logits = (const float*)d_in[0];
  const int* target = (const int*)d_in[1];
  float* out = (float*)d_out;

  double* acc = (double*)d_ws;
  float* bufbase = (float*)((char*)d_ws + 4096);
  float* probs = bufbase;
  float* pred_b = bufbase + Nc;
  float* gt_b = bufbase + 2 * Nc;
  float* scratch = bufbase + 3 * Nc;

  hipMemsetAsync(d_ws, 0, 4096, stream);

  elem_reduce_kernel<<<dim3(B * 64), dim3(256), 0, stream>>>(logits, target,
                                                             probs, acc);
  dim3 g2(W / 64, H / 4, B), b2(256);
  boundary_probs_kernel<<<g2, b2, 0, stream>>>(probs, pred_b);
  boundary_gt_kernel<<<g2, b2, 0, stream>>>(target, gt_b);

  // pred chain: pred_d = dilate1^d(pred_b), compare vs gt_b
  float* pp[2] = {scratch, probs};  // probs is free after boundary kernel
  const float* cur = pred_b;
  for (int d = 1; d <= 10; ++d) {
    float* nxt = pp[(d - 1) & 1];
    dilate_diff_kernel<<<g2, b2, 0, stream>>>(cur, gt_b, nxt, acc + 48 + d);
    cur = nxt;
  }
  // gt chain: gt_d = dilate1^d(gt_b), compare vs pred_b
  cur = gt_b;
  for (int d = 1; d <= 10; ++d) {
    float* nxt = pp[(d - 1) & 1];
    dilate_diff_kernel<<<g2, b2, 0, stream>>>(cur, pred_b, nxt, acc + 58 + d);
    cur = nxt;
  }
  finalize_kernel<<<1, 64, 0, stream>>>(acc, out);
}

// Round 2
// 286.051 us; speedup vs baseline: 14.4088x; 14.4088x over previous
//
#include <hip/hip_runtime.h>
#include <math.h>

namespace {

constexpr int B = 16, H = 512, W = 512;
constexpr int HWc = H * W;                 // 262144
constexpr size_t Nc = (size_t)B * HWc;     // 4194304

// chain tiling: central 64x32, halo 10 -> LDS tile 84 x 52
constexpr int TX = 64, TY = 32, HALO = 10;
constexpr int LW = TX + 2 * HALO;  // 84
constexpr int LH = TY + 2 * HALO;  // 52
constexpr int NBX = W / TX, NBY = H / TY;          // 8, 16
constexpr int NCHAINBLK = NBX * NBY * B;           // 2048

// --- block-wide sum over 256 threads (4 waves of 64). Valid on tid==0 only.
__device__ __forceinline__ float block_reduce_256(float v, float* sm, int tid) {
#pragma unroll
  for (int off = 32; off > 0; off >>= 1) v += __shfl_down(v, off);
  int lane = tid & 63, wid = tid >> 6;
  if (lane == 0) sm[wid] = v;
  __syncthreads();
  float r = 0.f;
  if (tid == 0) r = sm[0] + sm[1] + sm[2] + sm[3];
  __syncthreads();
  return r;
}

// partial layout (floats):
//   bce_p[1024], sp_p[1024], st_p[1024], spt_p[1024], chain_p[2][2048]
__global__ void elem_reduce_kernel(const float* __restrict__ logits,
                                   const int* __restrict__ target,
                                   float* __restrict__ probs,
                                   float* __restrict__ bce_p,
                                   float* __restrict__ sp_p,
                                   float* __restrict__ st_p,
                                   float* __restrict__ spt_p) {
  __shared__ float sm[4];
  int tid = threadIdx.x;
  int blk = blockIdx.x;
  int b = blk >> 6;
  int chunk = blk & 63;
  int base = b * HWc + chunk * 4096;
  float s_bce = 0.f, s_p = 0.f, s_t = 0.f, s_pt = 0.f;
#pragma unroll
  for (int k = 0; k < 4; ++k) {
    int idx = base + k * 1024 + tid * 4;
    float4 x4 = *reinterpret_cast<const float4*>(logits + idx);
    int4 t4 = *reinterpret_cast<const int4*>(target + idx);
    float xs[4] = {x4.x, x4.y, x4.z, x4.w};
    int ts[4] = {t4.x, t4.y, t4.z, t4.w};
    float ps[4];
#pragma unroll
    for (int j = 0; j < 4; ++j) {
      float x = xs[j];
      float t = (float)ts[j];
      s_bce += fmaxf(x, 0.f) - x * t + log1pf(expf(-fabsf(x)));
      float p = 1.f / (1.f + expf(-x));
      ps[j] = p;
      s_p += p;
      s_t += t;
      s_pt += p * t;
    }
    *reinterpret_cast<float4*>(probs + idx) =
        make_float4(ps[0], ps[1], ps[2], ps[3]);
  }
  float r;
  r = block_reduce_256(s_bce, sm, tid);
  if (tid == 0) bce_p[blk] = r;
  r = block_reduce_256(s_p, sm, tid);
  if (tid == 0) sp_p[blk] = r;
  r = block_reduce_256(s_t, sm, tid);
  if (tid == 0) st_p[blk] = r;
  r = block_reduce_256(s_pt, sm, tid);
  if (tid == 0) spt_p[blk] = r;
}

__global__ void boundary_probs_kernel(const float* __restrict__ probs,
                                      float* __restrict__ outb) {
  int tid = threadIdx.x;
  int tx = tid & 63, ty = tid >> 6;
  int x = blockIdx.x * 64 + tx;
  int y = blockIdx.y * 4 + ty;
  int b = blockIdx.z;
  const float* img = probs + (size_t)b * HWc;
  float mx = -1e30f, mn = 1e30f;
#pragma unroll
  for (int dy = -1; dy <= 1; ++dy) {
    int yy = min(max(y + dy, 0), H - 1);
#pragma unroll
    for (int dx = -1; dx <= 1; ++dx) {
      int xx = min(max(x + dx, 0), W - 1);
      float v = img[yy * W + xx];
      mx = fmaxf(mx, v);
      mn = fminf(mn, v);
    }
  }
  outb[(size_t)b * HWc + y * W + x] = mx - mn;
}

__global__ void boundary_gt_kernel(const int* __restrict__ target,
                                   float* __restrict__ outb) {
  int tid = threadIdx.x;
  int tx = tid & 63, ty = tid >> 6;
  int x = blockIdx.x * 64 + tx;
  int y = blockIdx.y * 4 + ty;
  int b = blockIdx.z;
  const int* img = target + (size_t)b * HWc;
  int mx = -2147483647, mn = 2147483647;
#pragma unroll
  for (int dy = -1; dy <= 1; ++dy) {
    int yy = min(max(y + dy, 0), H - 1);
#pragma unroll
    for (int dx = -1; dx <= 1; ++dx) {
      int xx = min(max(x + dx, 0), W - 1);
      int v = img[yy * W + xx];
      mx = max(mx, v);
      mn = min(mn, v);
    }
  }
  outb[(size_t)b * HWc + y * W + x] = (float)(mx - mn);
}

// Fused 10-step dilation chain. base = map being dilated, other = fixed map.
// Accumulates sum over central pixels of sum_d (d/10)*|dilate^d(base) - other|
// into one partial per block. LDS ping-pong, separable H/V max3.
// Replicated (clamped) halo loads reproduce clamped-window semantics for all
// in-image pixels: padded values are <= their clamped image values and the
// clamped pixel itself is always inside the raw window.
__global__ void __launch_bounds__(256) chain_kernel(
    const float* __restrict__ base, const float* __restrict__ other,
    float* __restrict__ partial) {
  __shared__ float A[LH][LW];
  __shared__ float Bb[LH][LW];
  __shared__ float sm[4];
  int tid = threadIdx.x;
  int tx = tid & 63, ty = tid >> 6;
  int x0 = blockIdx.x * TX, y0 = blockIdx.y * TY;
  int b = blockIdx.z;
  const float* bimg = base + (size_t)b * HWc;
  const float* oimg = other + (size_t)b * HWc;

  // load base tile with clamped halo
  for (int rr = ty; rr < LH; rr += 4) {
    int gy = min(max(y0 + rr - HALO, 0), H - 1);
#pragma unroll
    for (int ci = 0; ci < 2; ++ci) {
      int cc = tx + ci * 64;
      if (cc < LW) {
        int gx = min(max(x0 + cc - HALO, 0), W - 1);
        A[rr][cc] = bimg[gy * W + gx];
      }
    }
  }
  // other: central pixels owned by this thread (col tx, rows ty+4k)
  float o[8];
#pragma unroll
  for (int k = 0; k < 8; ++k) o[k] = oimg[(y0 + ty + 4 * k) * W + x0 + tx];
  __syncthreads();

  float acc = 0.f;
#pragma unroll
  for (int d = 1; d <= 10; ++d) {
    const int h = 10 - d;  // halo remaining after this step
    // H pass: rows keep old halo (h+1), cols shrink to halo h. A -> Bb
    {
      const int nr = TY + 2 * (h + 1), nc = TX + 2 * h;
      const int r0 = HALO - (h + 1), c0 = HALO - h;
      for (int rr = ty; rr < nr; rr += 4) {
        int ri = r0 + rr;
        for (int cc = tx; cc < nc; cc += 64) {
          int ci = c0 + cc;
          float v = fmaxf(fmaxf(A[ri][ci - 1], A[ri][ci]), A[ri][ci + 1]);
          Bb[ri][ci] = v;
        }
      }
    }
    __syncthreads();
    // V pass: rows shrink to halo h. Bb -> A
    {
      const int nr = TY + 2 * h, nc = TX + 2 * h;
      const int r0 = HALO - h, c0 = HALO - h;
      for (int rr = ty; rr < nr; rr += 4) {
        int ri = r0 + rr;
        for (int cc = tx; cc < nc; cc += 64) {
          int ci = c0 + cc;
          float v = fmaxf(fmaxf(Bb[ri - 1][ci], Bb[ri][ci]), Bb[ri + 1][ci]);
          A[ri][ci] = v;
        }
      }
    }
    __syncthreads();
    // accumulate weighted |dilate^d - other| over central pixels
    const float wd = 0.1f * (float)d;
#pragma unroll
    for (int k = 0; k < 8; ++k) {
      float v = A[HALO + ty + 4 * k][HALO + tx];
      acc += wd * fabsf(v - o[k]);
    }
    // after-V barrier already ordered Bb reads; next H writes Bb, reads A
    // (A only read here) -> need barrier so all diff reads of A complete
    // before next V overwrites A. Next V is preceded by a barrier (after H),
    // and H does not write A, so we're safe without an extra barrier only if
    // H's Bb writes don't race V's old Bb reads -- they were ordered by the
    // post-V barrier above. Diff reads A; next writer of A is V, separated by
    // the post-H barrier. OK.
  }

  float r = block_reduce_256(acc, sm, tid);
  if (tid == 0) {
    int blkflat = (blockIdx.z * gridDim.y + blockIdx.y) * gridDim.x + blockIdx.x;
    partial[blkflat] = r;
  }
}

__global__ void finalize_kernel(const float* __restrict__ bce_p,
                                const float* __restrict__ sp_p,
                                const float* __restrict__ st_p,
                                const float* __restrict__ spt_p,
                                const float* __restrict__ chain0,
                                const float* __restrict__ chain1,
                                float* __restrict__ out) {
  __shared__ float sm[4];
  __shared__ double img_terms[16][2];  // dice, ft per image
  int tid = threadIdx.x;

  // bce sum (1024 partials)
  float s = 0.f;
  for (int i = tid; i < 1024; i += 256) s += bce_p[i];
  float bce_sum = block_reduce_256(s, sm, tid);

  // chain sums (2 x 2048 partials)
  s = 0.f;
  for (int i = tid; i < NCHAINBLK; i += 256) s += chain0[i];
  float hd0 = block_reduce_256(s, sm, tid);
  s = 0.f;
  for (int i = tid; i < NCHAINBLK; i += 256) s += chain1[i];
  float hd1 = block_reduce_256(s, sm, tid);

  // per-image dice / focal-tversky
  if (tid < 16) {
    double sp = 0.0, st = 0.0, spt = 0.0;
    for (int j = 0; j < 64; ++j) {
      sp += (double)sp_p[tid * 64 + j];
      st += (double)st_p[tid * 64 + j];
      spt += (double)spt_p[tid * 64 + j];
    }
    double dice = (2.0 * spt + 1e-6) / (sp + st + 1e-6 + 1e-7);
    double tv = (spt + 1e-6) /
                (spt + 0.7 * (sp - spt) + 0.3 * (st - spt) + 1e-6 + 1e-7);
    img_terms[tid][0] = 1.0 - dice;
    img_terms[tid][1] = pow(1.0 - tv, 0.75);
  }
  __syncthreads();
  if (tid == 0) {
    const double Nd = (double)Nc;
    double dice_l = 0.0, ft_l = 0.0;
    for (int i = 0; i < 16; ++i) {
      dice_l += img_terms[i][0];
      ft_l += img_terms[i][1];
    }
    dice_l /= 16.0;
    ft_l /= 16.0;
    double bce = (double)bce_sum / Nd;
    double hd = (((double)hd0 + (double)hd1) / Nd) / (5.5 + 1e-8);
    out[0] = (float)(bce + dice_l + ft_l + 0.1 * hd);
  }
}

}  // namespace

extern "C" void kernel_launch(void* const* d_in, const int* in_sizes, int n_in,
                              void* d_out, int out_size, void* d_ws,
                              size_t ws_size, hipStream_t stream) {
  const float* logits = (const float*)d_in[0];
  const int* target = (const int*)d_in[1];
  float* out = (float*)d_out;

  float* probs = (float*)d_ws;
  float* pred_b = probs + Nc;
  float* gt_b = probs + 2 * Nc;
  float* part = probs + 3 * Nc;
  float* bce_p = part;           // 1024
  float* sp_p = part + 1024;     // 1024
  float* st_p = part + 2048;     // 1024
  float* spt_p = part + 3072;    // 1024
  float* chain0 = part + 4096;   // 2048
  float* chain1 = part + 6144;   // 2048

  elem_reduce_kernel<<<dim3(B * 64), dim3(256), 0, stream>>>(
      logits, target, probs, bce_p, sp_p, st_p, spt_p);
  dim3 g2(W / 64, H / 4, B), b2(256);
  boundary_probs_kernel<<<g2, b2, 0, stream>>>(probs, pred_b);
  boundary_gt_kernel<<<g2, b2, 0, stream>>>(target, gt_b);

  dim3 gc(NBX, NBY, B), bc(256);
  chain_kernel<<<gc, bc, 0, stream>>>(pred_b, gt_b, chain0);
  chain_kernel<<<gc, bc, 0, stream>>>(gt_b, pred_b, chain1);

  finalize_kernel<<<1, 256, 0, stream>>>(bce_p, sp_p, st_p, spt_p, chain0,
                                         chain1, out);
}

// Round 3
// 153.812 us; speedup vs baseline: 26.7966x; 1.8597x over previous
//
#include <hip/hip_runtime.h>
#include <math.h>

namespace {

constexpr int B = 16, H = 512, W = 512;
constexpr int HWc = H * W;                 // 262144
constexpr size_t Nc = (size_t)B * HWc;     // 4194304

// ---------------- DPP lane shifts ----------------
// wave_shr:1 (0x138): lane i <- lane i-1 (lane 0 keeps old)
// wave_shl:1 (0x130): lane i <- lane i+1 (lane 63 keeps old)
// old = own value => out-of-range lanes clamp to self. max3 is symmetric, so
// even a swapped direction interpretation yields an identical result.
template <int CTRL>
__device__ __forceinline__ float dpp_shift1(float v) {
  int i = __float_as_int(v);
  int r = __builtin_amdgcn_update_dpp(i, i, CTRL, 0xF, 0xF, false);
  return __int_as_float(r);
}
__device__ __forceinline__ float hmax3(float v) {
  return fmaxf(fmaxf(dpp_shift1<0x138>(v), v), dpp_shift1<0x130>(v));
}

// --- block-wide sum over 256 threads (4 waves of 64). Valid on tid==0 only.
__device__ __forceinline__ float block_reduce_256(float v, float* sm, int tid) {
#pragma unroll
  for (int off = 32; off > 0; off >>= 1) v += __shfl_down(v, off);
  int lane = tid & 63, wid = tid >> 6;
  if (lane == 0) sm[wid] = v;
  __syncthreads();
  float r = 0.f;
  if (tid == 0) r = sm[0] + sm[1] + sm[2] + sm[3];
  __syncthreads();
  return r;
}

// ---------------- prep: probs + BCE/dice partials + both boundary maps ------
// tile: central 64x32, halo 1 -> LDS 34x66 (sigmoid of logits, and target)
constexpr int PH = 34, PW = 66;

__global__ void __launch_bounds__(256) prep_kernel(
    const float* __restrict__ logits, const int* __restrict__ target,
    float* __restrict__ pred_b, float* __restrict__ gt_b,
    float* __restrict__ bce_p, float* __restrict__ sp_p,
    float* __restrict__ st_p, float* __restrict__ spt_p) {
  __shared__ float smP[PH][PW];
  __shared__ float smT[PH][PW];
  __shared__ float smr[4];
  int tid = threadIdx.x;
  int x0 = blockIdx.x * 64, y0 = blockIdx.y * 32, img = blockIdx.z;
  const float* L = logits + (size_t)img * HWc;
  const int* T = target + (size_t)img * HWc;

  for (int i = tid; i < PH * PW; i += 256) {
    int r = i / PW, c = i - r * PW;
    int gy = min(max(y0 - 1 + r, 0), H - 1);
    int gx = min(max(x0 - 1 + c, 0), W - 1);
    float x = L[gy * W + gx];
    smP[r][c] = 1.f / (1.f + expf(-x));
    smT[r][c] = (float)T[gy * W + gx];
  }
  __syncthreads();

  int tx = tid & 63, ty = tid >> 6;
  float s_bce = 0.f, s_p = 0.f, s_t = 0.f, s_pt = 0.f;
#pragma unroll
  for (int k = 0; k < 8; ++k) {
    int yy = ty + 4 * k;  // 0..31 within tile
    size_t idx = (size_t)img * HWc + (size_t)(y0 + yy) * W + x0 + tx;
    float xl = logits[idx];
    float t = smT[yy + 1][tx + 1];
    s_bce += fmaxf(xl, 0.f) - xl * t + log1pf(expf(-fabsf(xl)));
    float p = smP[yy + 1][tx + 1];
    s_p += p;
    s_t += t;
    s_pt += p * t;
    float mx = -1e30f, mn = 1e30f, gmx = -1e30f, gmn = 1e30f;
#pragma unroll
    for (int dy = 0; dy < 3; ++dy) {
#pragma unroll
      for (int dx = 0; dx < 3; ++dx) {
        float v = smP[yy + dy][tx + dx];
        mx = fmaxf(mx, v);
        mn = fminf(mn, v);
        float g = smT[yy + dy][tx + dx];
        gmx = fmaxf(gmx, g);
        gmn = fminf(gmn, g);
      }
    }
    pred_b[idx] = mx - mn;
    gt_b[idx] = gmx - gmn;
  }

  int blk = (blockIdx.z * gridDim.y + blockIdx.y) * gridDim.x + blockIdx.x;
  float r;
  r = block_reduce_256(s_bce, smr, tid);
  if (tid == 0) bce_p[blk] = r;
  r = block_reduce_256(s_p, smr, tid);
  if (tid == 0) sp_p[blk] = r;
  r = block_reduce_256(s_t, smr, tid);
  if (tid == 0) st_p[blk] = r;
  r = block_reduce_256(s_pt, smr, tid);
  if (tid == 0) spt_p[blk] = r;
}

// ---------------- chain: register-resident 10-step dilation -----------------
// One wave per (strip, band, img, chain). Lane owns one column: 52 rows in
// VGPRs (central 32 + vertical halo 10). Horizontal max3 via DPP lane shifts;
// vertical max3 via rolling registers. Central lanes: 10..52 (43 cols/strip).
// Strip s covers central cols [43s, 43s+42]; 12 strips cover 0..515 (mask
// col<512). Halo-lane corruption propagates 1 lane/step <= 10 = halo width.
__global__ void __launch_bounds__(64) chain_kernel(
    const float* __restrict__ pred_b, const float* __restrict__ gt_b,
    float* __restrict__ partial) {
  int lane = threadIdx.x;
  int strip = blockIdx.x;  // 0..11
  int band = blockIdx.y;   // 0..15
  int bz = blockIdx.z;     // 0..31
  int img = bz & 15, chain = bz >> 4;
  const float* src = (chain ? gt_b : pred_b) + (size_t)img * HWc;
  const float* oth = (chain ? pred_b : gt_b) + (size_t)img * HWc;
  int col = strip * 43 - 10 + lane;
  int colc = min(max(col, 0), W - 1);
  int y0 = band * 32;

  float a[52];
#pragma unroll
  for (int r = 0; r < 52; ++r) {
    int gy = min(max(y0 - 10 + r, 0), H - 1);
    a[r] = src[gy * W + colc];
  }
  float o[32];
#pragma unroll
  for (int k = 0; k < 32; ++k) o[k] = oth[(y0 + k) * W + colc];

  float acc = 0.f;
#pragma unroll
  for (int d = 1; d <= 10; ++d) {
    // valid rows from previous step: [d-1, 52-d]; outputs: [d, 51-d]
    float hp = hmax3(a[d - 1]);
    float hc = hmax3(a[d]);
#pragma unroll
    for (int r = d; r <= 51 - d; ++r) {
      float hn = hmax3(a[r + 1]);
      float nv = fmaxf(fmaxf(hp, hc), hn);
      hp = hc;
      hc = hn;
      a[r] = nv;
    }
    const float wd = 0.1f * (float)d;
#pragma unroll
    for (int k = 0; k < 32; ++k) acc += wd * fabsf(a[10 + k] - o[k]);
  }

  bool valid = (lane >= 10 && lane <= 52 && col < W);
  acc = valid ? acc : 0.f;
#pragma unroll
  for (int off = 32; off > 0; off >>= 1) acc += __shfl_down(acc, off);
  if (lane == 0) partial[(bz * 16 + band) * 12 + strip] = acc;
}

// ---------------- finalize ----------------
__global__ void finalize_kernel(const float* __restrict__ bce_p,
                                const float* __restrict__ sp_p,
                                const float* __restrict__ st_p,
                                const float* __restrict__ spt_p,
                                const float* __restrict__ chain_p,
                                float* __restrict__ out) {
  __shared__ float smr[4];
  __shared__ double img_terms[16][2];
  int tid = threadIdx.x;

  float s = 0.f;
  for (int i = tid; i < 2048; i += 256) s += bce_p[i];
  float bce_sum = block_reduce_256(s, smr, tid);

  s = 0.f;
  for (int i = tid; i < 6144; i += 256) s += chain_p[i];
  float hd_sum = block_reduce_256(s, smr, tid);

  if (tid < 16) {
    double sp = 0.0, st = 0.0, spt = 0.0;
    for (int j = 0; j < 128; ++j) {
      sp += (double)sp_p[tid * 128 + j];
      st += (double)st_p[tid * 128 + j];
      spt += (double)spt_p[tid * 128 + j];
    }
    double dice = (2.0 * spt + 1e-6) / (sp + st + 1e-6 + 1e-7);
    double tv = (spt + 1e-6) /
                (spt + 0.7 * (sp - spt) + 0.3 * (st - spt) + 1e-6 + 1e-7);
    img_terms[tid][0] = 1.0 - dice;
    img_terms[tid][1] = pow(1.0 - tv, 0.75);
  }
  __syncthreads();
  if (tid == 0) {
    const double Nd = (double)Nc;
    double dice_l = 0.0, ft_l = 0.0;
    for (int i = 0; i < 16; ++i) {
      dice_l += img_terms[i][0];
      ft_l += img_terms[i][1];
    }
    dice_l /= 16.0;
    ft_l /= 16.0;
    double bce = (double)bce_sum / Nd;
    double hd = ((double)hd_sum / Nd) / (5.5 + 1e-8);
    out[0] = (float)(bce + dice_l + ft_l + 0.1 * hd);
  }
}

}  // namespace

extern "C" void kernel_launch(void* const* d_in, const int* in_sizes, int n_in,
                              void* d_out, int out_size, void* d_ws,
                              size_t ws_size, hipStream_t stream) {
  const float* logits = (const float*)d_in[0];
  const int* target = (const int*)d_in[1];
  float* out = (float*)d_out;

  float* pred_b = (float*)d_ws;
  float* gt_b = pred_b + Nc;
  float* part = pred_b + 2 * Nc;
  float* bce_p = part;            // 2048
  float* sp_p = part + 2048;      // 2048
  float* st_p = part + 4096;      // 2048
  float* spt_p = part + 6144;     // 2048
  float* chain_p = part + 8192;   // 6144

  prep_kernel<<<dim3(8, 16, B), dim3(256), 0, stream>>>(
      logits, target, pred_b, gt_b, bce_p, sp_p, st_p, spt_p);
  chain_kernel<<<dim3(12, 16, 32), dim3(64), 0, stream>>>(pred_b, gt_b,
                                                          chain_p);
  finalize_kernel<<<1, 256, 0, stream>>>(bce_p, sp_p, st_p, spt_p, chain_p,
                                         out);
}

// Round 4
// 148.665 us; speedup vs baseline: 27.7243x; 1.0346x over previous
//
#include <hip/hip_runtime.h>
#include <math.h>

namespace {

constexpr int B = 16, H = 512, W = 512;
constexpr int HWc = H * W;                 // 262144
constexpr size_t Nc = (size_t)B * HWc;     // 4194304

// ---------------- DPP lane shifts ----------------
// wave_shr:1 (0x138): lane i <- lane i-1 (lane 0 keeps old)
// wave_shl:1 (0x130): lane i <- lane i+1 (lane 63 keeps old)
// old = own value => out-of-range lanes clamp to self. max3 is symmetric, so
// direction interpretation cannot change the result.
template <int CTRL>
__device__ __forceinline__ float dpp_shift1(float v) {
  int i = __float_as_int(v);
  int r = __builtin_amdgcn_update_dpp(i, i, CTRL, 0xF, 0xF, false);
  return __int_as_float(r);
}
__device__ __forceinline__ float hmax3(float v) {
  return fmaxf(fmaxf(dpp_shift1<0x138>(v), v), dpp_shift1<0x130>(v));
}

// --- block-wide sum over 256 threads (4 waves of 64). Valid on tid==0 only.
__device__ __forceinline__ float block_reduce_256(float v, float* sm, int tid) {
#pragma unroll
  for (int off = 32; off > 0; off >>= 1) v += __shfl_down(v, off);
  int lane = tid & 63, wid = tid >> 6;
  if (lane == 0) sm[wid] = v;
  __syncthreads();
  float r = 0.f;
  if (tid == 0) r = sm[0] + sm[1] + sm[2] + sm[3];
  __syncthreads();
  return r;
}

// ---------------- prep: probs + BCE/dice partials + both boundary maps ------
// tile: central 64x32, halo 1 -> LDS 34x66 (sigmoid of logits, and target)
constexpr int PH = 34, PW = 66;

__global__ void __launch_bounds__(256) prep_kernel(
    const float* __restrict__ logits, const int* __restrict__ target,
    float* __restrict__ pred_b, float* __restrict__ gt_b,
    float* __restrict__ bce_p, float* __restrict__ sp_p,
    float* __restrict__ st_p, float* __restrict__ spt_p) {
  __shared__ float smP[PH][PW];
  __shared__ float smT[PH][PW];
  __shared__ float smr[4];
  int tid = threadIdx.x;
  int x0 = blockIdx.x * 64, y0 = blockIdx.y * 32, img = blockIdx.z;
  const float* L = logits + (size_t)img * HWc;
  const int* T = target + (size_t)img * HWc;

  for (int i = tid; i < PH * PW; i += 256) {
    int r = i / PW, c = i - r * PW;
    int gy = min(max(y0 - 1 + r, 0), H - 1);
    int gx = min(max(x0 - 1 + c, 0), W - 1);
    float x = L[gy * W + gx];
    smP[r][c] = 1.f / (1.f + expf(-x));
    smT[r][c] = (float)T[gy * W + gx];
  }
  __syncthreads();

  int tx = tid & 63, ty = tid >> 6;
  float s_bce = 0.f, s_p = 0.f, s_t = 0.f, s_pt = 0.f;
#pragma unroll
  for (int k = 0; k < 8; ++k) {
    int yy = ty + 4 * k;  // 0..31 within tile
    size_t idx = (size_t)img * HWc + (size_t)(y0 + yy) * W + x0 + tx;
    float xl = logits[idx];
    float t = smT[yy + 1][tx + 1];
    s_bce += fmaxf(xl, 0.f) - xl * t + log1pf(expf(-fabsf(xl)));
    float p = smP[yy + 1][tx + 1];
    s_p += p;
    s_t += t;
    s_pt += p * t;
    float mx = -1e30f, mn = 1e30f, gmx = -1e30f, gmn = 1e30f;
#pragma unroll
    for (int dy = 0; dy < 3; ++dy) {
#pragma unroll
      for (int dx = 0; dx < 3; ++dx) {
        float v = smP[yy + dy][tx + dx];
        mx = fmaxf(mx, v);
        mn = fminf(mn, v);
        float g = smT[yy + dy][tx + dx];
        gmx = fmaxf(gmx, g);
        gmn = fminf(gmn, g);
      }
    }
    pred_b[idx] = mx - mn;
    gt_b[idx] = gmx - gmn;
  }

  int blk = (blockIdx.z * gridDim.y + blockIdx.y) * gridDim.x + blockIdx.x;
  float r;
  r = block_reduce_256(s_bce, smr, tid);
  if (tid == 0) bce_p[blk] = r;
  r = block_reduce_256(s_p, smr, tid);
  if (tid == 0) sp_p[blk] = r;
  r = block_reduce_256(s_t, smr, tid);
  if (tid == 0) st_p[blk] = r;
  r = block_reduce_256(s_pt, smr, tid);
  if (tid == 0) spt_p[blk] = r;
}

// ---------------- chain: register-resident 10-step dilation -----------------
// 4 independent waves per 256-thread block (lifts the 1-wave-workgroup
// occupancy cap seen in R3: 29% -> ~75%). Wave owns (strip, band, img, chain).
// Lane owns one column: 52 rows in VGPRs (central 32 + vertical halo 10).
// Horizontal max3 via DPP lane shifts; vertical max3 via rolling registers.
// Central lanes: 10..52 (43 cols/strip); 12 strips cover 516 cols (mask
// col<512). Halo-lane corruption propagates 1 lane/step <= 10 = halo width.
__global__ void __launch_bounds__(256) chain_kernel(
    const float* __restrict__ pred_b, const float* __restrict__ gt_b,
    float* __restrict__ partial) {
  int tid = threadIdx.x;
  int lane = tid & 63;
  int wv = tid >> 6;
  int strip = blockIdx.x * 4 + wv;  // 0..11
  int band = blockIdx.y;            // 0..15
  int bz = blockIdx.z;              // 0..31
  int img = bz & 15, chain = bz >> 4;
  const float* src = (chain ? gt_b : pred_b) + (size_t)img * HWc;
  const float* oth = (chain ? pred_b : gt_b) + (size_t)img * HWc;
  int col = strip * 43 - 10 + lane;
  int colc = min(max(col, 0), W - 1);
  int y0 = band * 32;

  float a[52];
#pragma unroll
  for (int r = 0; r < 52; ++r) {
    int gy = min(max(y0 - 10 + r, 0), H - 1);
    a[r] = src[gy * W + colc];
  }
  float o[32];
#pragma unroll
  for (int k = 0; k < 32; ++k) o[k] = oth[(y0 + k) * W + colc];

  float acc = 0.f;
#pragma unroll
  for (int d = 1; d <= 10; ++d) {
    // valid rows from previous step: [d-1, 52-d]; outputs: [d, 51-d]
    float hp = hmax3(a[d - 1]);
    float hc = hmax3(a[d]);
#pragma unroll
    for (int r = d; r <= 51 - d; ++r) {
      float hn = hmax3(a[r + 1]);
      float nv = fmaxf(fmaxf(hp, hc), hn);
      hp = hc;
      hc = hn;
      a[r] = nv;
    }
    const float wd = 0.1f * (float)d;
#pragma unroll
    for (int k = 0; k < 32; ++k) acc += wd * fabsf(a[10 + k] - o[k]);
  }

  bool valid = (lane >= 10 && lane <= 52 && col < W);
  acc = valid ? acc : 0.f;
#pragma unroll
  for (int off = 32; off > 0; off >>= 1) acc += __shfl_down(acc, off);
  if (lane == 0) partial[(bz * 16 + band) * 12 + strip] = acc;
}

// ---------------- finalize ----------------
__global__ void finalize_kernel(const float* __restrict__ bce_p,
                                const float* __restrict__ sp_p,
                                const float* __restrict__ st_p,
                                const float* __restrict__ spt_p,
                                const float* __restrict__ chain_p,
                                float* __restrict__ out) {
  __shared__ float smr[4];
  __shared__ double img_terms[16][2];
  int tid = threadIdx.x;

  float s = 0.f;
  for (int i = tid; i < 2048; i += 256) s += bce_p[i];
  float bce_sum = block_reduce_256(s, smr, tid);

  s = 0.f;
  for (int i = tid; i < 6144; i += 256) s += chain_p[i];
  float hd_sum = block_reduce_256(s, smr, tid);

  if (tid < 16) {
    double sp = 0.0, st = 0.0, spt = 0.0;
    for (int j = 0; j < 128; ++j) {
      sp += (double)sp_p[tid * 128 + j];
      st += (double)st_p[tid * 128 + j];
      spt += (double)spt_p[tid * 128 + j];
    }
    double dice = (2.0 * spt + 1e-6) / (sp + st + 1e-6 + 1e-7);
    double tv = (spt + 1e-6) /
                (spt + 0.7 * (sp - spt) + 0.3 * (st - spt) + 1e-6 + 1e-7);
    img_terms[tid][0] = 1.0 - dice;
    img_terms[tid][1] = pow(1.0 - tv, 0.75);
  }
  __syncthreads();
  if (tid == 0) {
    const double Nd = (double)Nc;
    double dice_l = 0.0, ft_l = 0.0;
    for (int i = 0; i < 16; ++i) {
      dice_l += img_terms[i][0];
      ft_l += img_terms[i][1];
    }
    dice_l /= 16.0;
    ft_l /= 16.0;
    double bce = (double)bce_sum / Nd;
    double hd = ((double)hd_sum / Nd) / (5.5 + 1e-8);
    out[0] = (float)(bce + dice_l + ft_l + 0.1 * hd);
  }
}

}  // namespace

extern "C" void kernel_launch(void* const* d_in, const int* in_sizes, int n_in,
                              void* d_out, int out_size, void* d_ws,
                              size_t ws_size, hipStream_t stream) {
  const float* logits = (const float*)d_in[0];
  const int* target = (const int*)d_in[1];
  float* out = (float*)d_out;

  float* pred_b = (float*)d_ws;
  float* gt_b = pred_b + Nc;
  float* part = pred_b + 2 * Nc;
  float* bce_p = part;            // 2048
  float* sp_p = part + 2048;      // 2048
  float* st_p = part + 4096;      // 2048
  float* spt_p = part + 6144;     // 2048
  float* chain_p = part + 8192;   // 6144

  prep_kernel<<<dim3(8, 16, B), dim3(256), 0, stream>>>(
      logits, target, pred_b, gt_b, bce_p, sp_p, st_p, spt_p);
  chain_kernel<<<dim3(3, 16, 32), dim3(256), 0, stream>>>(pred_b, gt_b,
                                                          chain_p);
  finalize_kernel<<<1, 256, 0, stream>>>(bce_p, sp_p, st_p, spt_p, chain_p,
                                         out);
}

// Round 5
// 148.294 us; speedup vs baseline: 27.7936x; 1.0025x over previous
//
#include <hip/hip_runtime.h>
#include <math.h>

namespace {

constexpr int B = 16, H = 512, W = 512;
constexpr int HWc = H * W;                 // 262144
constexpr size_t Nc = (size_t)B * HWc;     // 4194304

// ---------------- DPP lane shifts ----------------
// wave_shr:1 (0x138): lane i <- lane i-1 (lane 0 keeps old)
// wave_shl:1 (0x130): lane i <- lane i+1 (lane 63 keeps old)
// old = own value => out-of-range lanes clamp to self. max3 is symmetric, so
// direction interpretation cannot change the result.
template <int CTRL>
__device__ __forceinline__ float dpp_shift1(float v) {
  int i = __float_as_int(v);
  int r = __builtin_amdgcn_update_dpp(i, i, CTRL, 0xF, 0xF, false);
  return __int_as_float(r);
}
__device__ __forceinline__ float hmax3(float v) {
  return fmaxf(fmaxf(dpp_shift1<0x138>(v), v), dpp_shift1<0x130>(v));
}

// --- block-wide sum over 256 threads (4 waves of 64). Valid on tid==0 only.
__device__ __forceinline__ float block_reduce_256(float v, float* sm, int tid) {
#pragma unroll
  for (int off = 32; off > 0; off >>= 1) v += __shfl_down(v, off);
  int lane = tid & 63, wid = tid >> 6;
  if (lane == 0) sm[wid] = v;
  __syncthreads();
  float r = 0.f;
  if (tid == 0) r = sm[0] + sm[1] + sm[2] + sm[3];
  __syncthreads();
  return r;
}

// ---------------- prep: probs + BCE/dice partials + both boundary maps ------
// tile: central 64x32, halo 1 -> LDS 34x66 (sigmoid of logits, and target)
constexpr int PH = 34, PW = 66;

__global__ void __launch_bounds__(256) prep_kernel(
    const float* __restrict__ logits, const int* __restrict__ target,
    float* __restrict__ pred_b, float* __restrict__ gt_b,
    float* __restrict__ bce_p, float* __restrict__ sp_p,
    float* __restrict__ st_p, float* __restrict__ spt_p) {
  __shared__ float smP[PH][PW];
  __shared__ float smT[PH][PW];
  __shared__ float smr[4];
  int tid = threadIdx.x;
  int x0 = blockIdx.x * 64, y0 = blockIdx.y * 32, img = blockIdx.z;
  const float* L = logits + (size_t)img * HWc;
  const int* T = target + (size_t)img * HWc;

  for (int i = tid; i < PH * PW; i += 256) {
    int r = i / PW, c = i - r * PW;
    int gy = min(max(y0 - 1 + r, 0), H - 1);
    int gx = min(max(x0 - 1 + c, 0), W - 1);
    float x = L[gy * W + gx];
    smP[r][c] = 1.f / (1.f + expf(-x));
    smT[r][c] = (float)T[gy * W + gx];
  }
  __syncthreads();

  int tx = tid & 63, ty = tid >> 6;
  float s_bce = 0.f, s_p = 0.f, s_t = 0.f, s_pt = 0.f;
#pragma unroll
  for (int k = 0; k < 8; ++k) {
    int yy = ty + 4 * k;  // 0..31 within tile
    size_t idx = (size_t)img * HWc + (size_t)(y0 + yy) * W + x0 + tx;
    float xl = logits[idx];
    float t = smT[yy + 1][tx + 1];
    s_bce += fmaxf(xl, 0.f) - xl * t + log1pf(expf(-fabsf(xl)));
    float p = smP[yy + 1][tx + 1];
    s_p += p;
    s_t += t;
    s_pt += p * t;
    float mx = -1e30f, mn = 1e30f, gmx = -1e30f, gmn = 1e30f;
#pragma unroll
    for (int dy = 0; dy < 3; ++dy) {
#pragma unroll
      for (int dx = 0; dx < 3; ++dx) {
        float v = smP[yy + dy][tx + dx];
        mx = fmaxf(mx, v);
        mn = fminf(mn, v);
        float g = smT[yy + dy][tx + dx];
        gmx = fmaxf(gmx, g);
        gmn = fminf(gmn, g);
      }
    }
    pred_b[idx] = mx - mn;
    gt_b[idx] = gmx - gmn;
  }

  int blk = (blockIdx.z * gridDim.y + blockIdx.y) * gridDim.x + blockIdx.x;
  float r;
  r = block_reduce_256(s_bce, smr, tid);
  if (tid == 0) bce_p[blk] = r;
  r = block_reduce_256(s_p, smr, tid);
  if (tid == 0) sp_p[blk] = r;
  r = block_reduce_256(s_t, smr, tid);
  if (tid == 0) st_p[blk] = r;
  r = block_reduce_256(s_pt, smr, tid);
  if (tid == 0) spt_p[blk] = r;
}

// ---------------- chain: register-resident 10-step dilation -----------------
// 4 independent waves per 256-thread block. Wave owns (strip, band, img,
// chain). Lane owns one column: 52 rows in VGPRs (central 32 + vertical halo
// 10). Horizontal max3 via DPP lane shifts; vertical max3 via rolling
// registers. Central lanes: 10..52 (43 cols/strip); 12 strips cover 516 cols
// (mask col<512). Halo corruption propagates 1 lane/step <= 10 = halo width.
// __launch_bounds__(256, 4): allow ~128 VGPRs so a[52]+o[32] stay resident --
// at the default 60-VGPR budget the compiler remat-reloads o[] from global in
// every step (R4: ~500 MB L1/L2 reload traffic, VALUBusy 41%).
__global__ void __launch_bounds__(256, 4) chain_kernel(
    const float* __restrict__ pred_b, const float* __restrict__ gt_b,
    float* __restrict__ partial) {
  int tid = threadIdx.x;
  int lane = tid & 63;
  int wv = tid >> 6;
  int strip = blockIdx.x * 4 + wv;  // 0..11
  int band = blockIdx.y;            // 0..15
  int bz = blockIdx.z;              // 0..31
  int img = bz & 15, chain = bz >> 4;
  const float* src = (chain ? gt_b : pred_b) + (size_t)img * HWc;
  const float* oth = (chain ? pred_b : gt_b) + (size_t)img * HWc;
  int col = strip * 43 - 10 + lane;
  int colc = min(max(col, 0), W - 1);
  int y0 = band * 32;

  float a[52];
#pragma unroll
  for (int r = 0; r < 52; ++r) {
    int gy = min(max(y0 - 10 + r, 0), H - 1);
    a[r] = src[gy * W + colc];
  }
  float o[32];
#pragma unroll
  for (int k = 0; k < 32; ++k) o[k] = oth[(y0 + k) * W + colc];

  float acc = 0.f;
#pragma unroll
  for (int d = 1; d <= 10; ++d) {
    // valid rows from previous step: [d-1, 52-d]; outputs: [d, 51-d]
    float hp = hmax3(a[d - 1]);
    float hc = hmax3(a[d]);
#pragma unroll
    for (int r = d; r <= 51 - d; ++r) {
      float hn = hmax3(a[r + 1]);
      float nv = fmaxf(fmaxf(hp, hc), hn);
      hp = hc;
      hc = hn;
      a[r] = nv;
    }
    const float wd = 0.1f * (float)d;
#pragma unroll
    for (int k = 0; k < 32; ++k) acc += wd * fabsf(a[10 + k] - o[k]);
  }

  bool valid = (lane >= 10 && lane <= 52 && col < W);
  acc = valid ? acc : 0.f;
#pragma unroll
  for (int off = 32; off > 0; off >>= 1) acc += __shfl_down(acc, off);
  if (lane == 0) partial[(bz * 16 + band) * 12 + strip] = acc;
}

// ---------------- finalize ----------------
__global__ void finalize_kernel(const float* __restrict__ bce_p,
                                const float* __restrict__ sp_p,
                                const float* __restrict__ st_p,
                                const float* __restrict__ spt_p,
                                const float* __restrict__ chain_p,
                                float* __restrict__ out) {
  __shared__ float smr[4];
  __shared__ double img_terms[16][2];
  int tid = threadIdx.x;

  float s = 0.f;
  for (int i = tid; i < 2048; i += 256) s += bce_p[i];
  float bce_sum = block_reduce_256(s, smr, tid);

  s = 0.f;
  for (int i = tid; i < 6144; i += 256) s += chain_p[i];
  float hd_sum = block_reduce_256(s, smr, tid);

  if (tid < 16) {
    double sp = 0.0, st = 0.0, spt = 0.0;
    for (int j = 0; j < 128; ++j) {
      sp += (double)sp_p[tid * 128 + j];
      st += (double)st_p[tid * 128 + j];
      spt += (double)spt_p[tid * 128 + j];
    }
    double dice = (2.0 * spt + 1e-6) / (sp + st + 1e-6 + 1e-7);
    double tv = (spt + 1e-6) /
                (spt + 0.7 * (sp - spt) + 0.3 * (st - spt) + 1e-6 + 1e-7);
    img_terms[tid][0] = 1.0 - dice;
    img_terms[tid][1] = pow(1.0 - tv, 0.75);
  }
  __syncthreads();
  if (tid == 0) {
    const double Nd = (double)Nc;
    double dice_l = 0.0, ft_l = 0.0;
    for (int i = 0; i < 16; ++i) {
      dice_l += img_terms[i][0];
      ft_l += img_terms[i][1];
    }
    dice_l /= 16.0;
    ft_l /= 16.0;
    double bce = (double)bce_sum / Nd;
    double hd = ((double)hd_sum / Nd) / (5.5 + 1e-8);
    out[0] = (float)(bce + dice_l + ft_l + 0.1 * hd);
  }
}

}  // namespace

extern "C" void kernel_launch(void* const* d_in, const int* in_sizes, int n_in,
                              void* d_out, int out_size, void* d_ws,
                              size_t ws_size, hipStream_t stream) {
  const float* logits = (const float*)d_in[0];
  const int* target = (const int*)d_in[1];
  float* out = (float*)d_out;

  float* pred_b = (float*)d_ws;
  float* gt_b = pred_b + Nc;
  float* part = pred_b + 2 * Nc;
  float* bce_p = part;            // 2048
  float* sp_p = part + 2048;      // 2048
  float* st_p = part + 4096;      // 2048
  float* spt_p = part + 6144;     // 2048
  float* chain_p = part + 8192;   // 6144

  prep_kernel<<<dim3(8, 16, B), dim3(256), 0, stream>>>(
      logits, target, pred_b, gt_b, bce_p, sp_p, st_p, spt_p);
  chain_kernel<<<dim3(3, 16, 32), dim3(256), 0, stream>>>(pred_b, gt_b,
                                                          chain_p);
  finalize_kernel<<<1, 256, 0, stream>>>(bce_p, sp_p, st_p, spt_p, chain_p,
                                         out);
}